// Round 8
// baseline (3134.273 us; speedup 1.0000x reference)
//
#include <hip/hip_runtime.h>

// Problem constants (AttentionSpeller): T=128, B=32, E=H=512, U=1024, V=10000
#define T_STEPS 128
#define BATCH   32
#define HID     512
#define EMB     512
#define ULEN    1024
#define VOCAB   10000
#define G4H     2048   // 4*H

static inline int cdiv(int a, int b) { return (a + b - 1) / b; }

// ---------------------------------------------------------------------------
// Tiled fp32 GEMM, 64x64 tile / 4x4 micro-tile. Best for small-M shapes
// (8+ blocks/CU hide single-buffered staging latency — R5 post-mortem).
// ---------------------------------------------------------------------------
template <bool TRANSB>
__global__ __launch_bounds__(256)
void gemm_f32(const float* __restrict__ A, long lda, long sA,
              const float* __restrict__ Bm, long ldb, long sB,
              float* __restrict__ C, long ldc, long sC,
              int M, int N, int K, const float* __restrict__ bias)
{
    __shared__ float As[16][68];
    __shared__ float Bs[16][68];
    const int bz = blockIdx.z;
    A  += (size_t)bz * sA;
    Bm += (size_t)bz * sB;
    C  += (size_t)bz * sC;
    const int m0 = blockIdx.y * 64;
    const int n0 = blockIdx.x * 64;
    const int tid = threadIdx.x;
    const int tx = tid & 15, ty = tid >> 4;
    const int lr = tid >> 2;          // 0..63: tile row
    const int lk = (tid & 3) * 4;     // 0,4,8,12: k offset

    float acc[4][4] = {{0.f}};

    for (int k0 = 0; k0 < K; k0 += 16) {
        float4 av = *(const float4*)(A + (size_t)(m0 + lr) * lda + (k0 + lk));
        As[lk + 0][lr] = av.x; As[lk + 1][lr] = av.y;
        As[lk + 2][lr] = av.z; As[lk + 3][lr] = av.w;
        if (TRANSB) {
            const int nr = n0 + lr;
            float4 bv = make_float4(0.f, 0.f, 0.f, 0.f);
            if (nr < N) bv = *(const float4*)(Bm + (size_t)nr * ldb + (k0 + lk));
            Bs[lk + 0][lr] = bv.x; Bs[lk + 1][lr] = bv.y;
            Bs[lk + 2][lr] = bv.z; Bs[lk + 3][lr] = bv.w;
        } else {
            const int kr = tid >> 4;          // 0..15
            const int nc = (tid & 15) * 4;    // 0..60
            float4 bv = make_float4(0.f, 0.f, 0.f, 0.f);
            if (n0 + nc < N) bv = *(const float4*)(Bm + (size_t)(k0 + kr) * ldb + (n0 + nc));
            *(float4*)&Bs[kr][nc] = bv;
        }
        __syncthreads();
#pragma unroll
        for (int kk = 0; kk < 16; ++kk) {
            float ar[4], br[4];
#pragma unroll
            for (int i = 0; i < 4; i++) ar[i] = As[kk][ty * 4 + i];
#pragma unroll
            for (int j = 0; j < 4; j++) br[j] = Bs[kk][tx * 4 + j];
#pragma unroll
            for (int i = 0; i < 4; i++)
#pragma unroll
                for (int j = 0; j < 4; j++)
                    acc[i][j] += ar[i] * br[j];
        }
        __syncthreads();
    }
#pragma unroll
    for (int i = 0; i < 4; i++) {
        const int row = m0 + ty * 4 + i;
#pragma unroll
        for (int j = 0; j < 4; j++) {
            const int col = n0 + tx * 4 + j;
            if (col < N) {
                float v = acc[i][j];
                if (bias) v += bias[col];
                C[(size_t)row * ldc + col] = v;
            }
        }
    }
}

// ---------------------------------------------------------------------------
// bf16 split helpers: a = hi + lo with hi = bf16_rne(a), lo = bf16_rne(a-hi).
// Products hi*hi, hi*lo, lo*hi are exact in fp32; dropped lo*lo ~ 2^-17|ab|.
// ---------------------------------------------------------------------------
__device__ inline unsigned short f32_bf16(float x) {
    unsigned u = __float_as_uint(x);
    unsigned r = (u + 0x7FFFu + ((u >> 16) & 1u)) >> 16;
    return (unsigned short)r;
}
__device__ inline float bf16_f32(unsigned short h) {
    return __uint_as_float(((unsigned)h) << 16);
}

// Split src[N] f32 -> dhi[N], dlo[N] bf16. Grid-stride.
__global__ __launch_bounds__(256)
void conv_split(const float* __restrict__ src, unsigned short* __restrict__ dhi,
                unsigned short* __restrict__ dlo, int n)
{
    for (int i = blockIdx.x * 256 + threadIdx.x; i < n; i += gridDim.x * 256) {
        float a = src[i];
        unsigned short hi = f32_bf16(a);
        float r = a - bf16_f32(hi);
        dhi[i] = hi;
        dlo[i] = f32_bf16(r);
    }
}

// ---------------------------------------------------------------------------
// MFMA bf16-split GEMM: C[M,N] = A*B^T + bias, fp32-accurate via 3 passes
//   (Ahi*Bhi + Ahi*Blo + Alo*Bhi), A,B stored as bf16 hi/lo pairs [.,K].
// 128x128 tile, 4 waves in 2x2 (each 64x64 = 4x4 frags of 16x16x32 MFMA).
// M % 128 == 0; N guarded; K % 32 == 0.  (R7, verbatim — measured ~220us.)
// ---------------------------------------------------------------------------
typedef __attribute__((ext_vector_type(8))) short bf16x8;
typedef __attribute__((ext_vector_type(4))) float f32x4;

__global__ __launch_bounds__(256)
void gemm_bf16s(const unsigned short* __restrict__ Ahi,
                const unsigned short* __restrict__ Alo,
                const unsigned short* __restrict__ Bhi,
                const unsigned short* __restrict__ Blo,
                float* __restrict__ C, const float* __restrict__ bias,
                int M, int N, int K)
{
    __shared__ unsigned short Asm[128 * 32];    // [row][k] 8 KB
    __shared__ unsigned short Bsm[128 * 32];    // [col][k] 8 KB
    const int tid = threadIdx.x;
    const int m0 = blockIdx.y * 128;
    const int n0 = blockIdx.x * 128;
    const int w  = tid >> 6;                    // wave 0..3
    const int l  = tid & 63;
    const int wr = (w >> 1) * 64;               // wave row offset
    const int wc = (w & 1) * 64;                // wave col offset
    const int fr = l & 15;                      // frag row/col
    const int kb = l >> 4;                      // k-block 0..3 (8 bf16 each)

    f32x4 acc[4][4];
#pragma unroll
    for (int i = 0; i < 4; ++i)
#pragma unroll
        for (int j = 0; j < 4; ++j) acc[i][j] = (f32x4){0.f, 0.f, 0.f, 0.f};

    const int srow = tid >> 1;                  // staging row 0..127
    const int skh  = (tid & 1) * 16;            // staging k-offset (16 bf16)

#pragma unroll 1
    for (int pass = 0; pass < 3; ++pass) {
        const unsigned short* Ap = (pass == 2) ? Alo : Ahi;
        const unsigned short* Bp = (pass == 1) ? Blo : Bhi;
#pragma unroll 1
        for (int kt = 0; kt < K; kt += 32) {
            // ---- stage A tile 128x32 (32B per thread, contiguous) ----
            {
                const unsigned short* src = Ap + (size_t)(m0 + srow) * K + kt + skh;
                float4 v0 = *(const float4*)(src);
                float4 v1 = *(const float4*)(src + 8);
                *(float4*)&Asm[srow * 32 + skh] = v0;
                *(float4*)&Asm[srow * 32 + skh + 8] = v1;
            }
            // ---- stage B tile 128x32 (rows are W_out cols; guard N) ----
            {
                const int nr = n0 + srow;
                float4 v0 = make_float4(0.f, 0.f, 0.f, 0.f), v1 = v0;
                if (nr < N) {
                    const unsigned short* src = Bp + (size_t)nr * K + kt + skh;
                    v0 = *(const float4*)(src);
                    v1 = *(const float4*)(src + 8);
                }
                *(float4*)&Bsm[srow * 32 + skh] = v0;
                *(float4*)&Bsm[srow * 32 + skh + 8] = v1;
            }
            __syncthreads();
            // ---- fragments: lane holds 8 contiguous k at (row, kb*8) ----
            bf16x8 af[4], bf[4];
#pragma unroll
            for (int i = 0; i < 4; ++i)
                af[i] = *(const bf16x8*)&Asm[(wr + i * 16 + fr) * 32 + kb * 8];
#pragma unroll
            for (int j = 0; j < 4; ++j)
                bf[j] = *(const bf16x8*)&Bsm[(wc + j * 16 + fr) * 32 + kb * 8];
#pragma unroll
            for (int i = 0; i < 4; ++i)
#pragma unroll
                for (int j = 0; j < 4; ++j)
                    acc[i][j] = __builtin_amdgcn_mfma_f32_16x16x32_bf16(
                        af[i], bf[j], acc[i][j], 0, 0, 0);
            __syncthreads();
        }
    }

    // ---- epilogue: C/D layout col=lane&15, row=(lane>>4)*4+reg ----
#pragma unroll
    for (int i = 0; i < 4; ++i) {
#pragma unroll
        for (int j = 0; j < 4; ++j) {
            const int col = n0 + wc + j * 16 + fr;
            if (col < N) {
                const float bv = bias ? bias[col] : 0.f;
#pragma unroll
                for (int r = 0; r < 4; ++r) {
                    const int row = m0 + wr + i * 16 + kb * 4 + r;
                    C[(size_t)row * N + col] = acc[i][j][r] + bv;
                }
            }
        }
    }
}

// ---------------------------------------------------------------------------
// Persistent LSTM scan v9 — v8 compute + direct seq-slot exchange.
//
// v7 post-mortem (corrected understanding): the design was CORRECT (it
// passed) but polled with ACQUIRE at agent scope -> a cache invalidation
// per poll iteration per wave (~20us/step). v9 polls RELAXED (the same
// primitive the proven v8 barrier polls use: agent atomics bypass the
// non-coherent L2s), with NO acquire anywhere:
//  - producer: owner threads agent-store (write-through) their 64 h floats
//    to hslab[t][bid][64]; __syncthreads() drains vmcnt (proven v3
//    mechanism); tid0 agent-stores seq[t][bid] = scan_base + t + 1.
//  - consumer (step t): thread tid spins RELAXED on seq[t-1][tid] until it
//    equals the tag, then plain-reads the 64-float slot and f2-scatters it
//    into swizzled h_lds. Plain reads are fresh by first-touch induction:
//    any L2 copy of a slab line was fetched after SOME block on that XCD
//    observed the tag => after the producer's drained stores. A compiler
//    memory fence stops load hoisting (HW does not speculate past
//    branches). Removes the tree barrier's aggregate+release hop.
//  - seq tags (0x100/0x200 base) disambiguate the two scans; 0xAA poison
//    never matches; no flag zeroing needed.
//  - h_all stores become PLAIN (read only by later dispatches; dispatch
//    boundary flushes L2 — same guarantee gates/ctx already rely on).
// ---------------------------------------------------------------------------
__device__ inline float sigmoidf_(float x) { return 1.f / (1.f + expf(-x)); }

__global__ __launch_bounds__(256, 1)
void lstm_scan(const float* __restrict__ gp,    // (T*B*2048) x@W_ih^T + b_ih + b_hh
               const float* __restrict__ Whh,   // (2048 x 512) row-major
               const float* __restrict__ h0,    // (B*H) layer slice
               const float* __restrict__ c0,    // (B*H) layer slice
               float* __restrict__ h_all,       // (T*B*H) out
               float* __restrict__ hslab,       // (T*256*64) exchange slab
               unsigned* __restrict__ seq,      // (T*256) seq words
               unsigned scan_base)              // 0x100 scan1 / 0x200 scan2
{
    __shared__ float h_lds[BATCH * HID];        // 64 KB, XOR-swizzled float4s
    __shared__ float w_lds[8 * HID];            // 16 KB, same swizzle
    __shared__ float part[256 * 36];            // 36 KB partial sums

    const int tid  = threadIdx.x;
    const int bid  = blockIdx.x;
    const int hbase = bid * 2;

    // dot-phase identity: tid = bq*32 + ks
    const int ks = tid & 31;                    // 0..31 k-slice of 16
    const int bq = tid >> 5;                    // 0..7 batch-quarter (4 rows)
    const int kl = ks & 7;

    // cell-phase identity: tid = b*8 + nl
    const int b    = tid >> 3;                  // 0..31
    const int nl   = tid & 7;                   // 0..7
    const int j    = nl & 1;
    const int lane = tid & 63;
    const int sbase = lane & ~7;                // shuffle group base lane
    const int n = ((nl >> 1) << 9) + hbase + j; // gate column 0..2047

    // ---- stage this block's 8 W_hh rows -> LDS once (swizzled) ----
#pragma unroll
    for (int i = 0; i < 4; ++i) {
        const int vi = i * 256 + tid;           // 0..1023 f4 index
        const int c  = vi >> 7;                 // 0..7 col slot
        const int f  = vi & 127;                // f4 within row
        const int nd = ((c >> 1) << 9) + hbase + (c & 1);
        float4 v = *(const float4*)(Whh + (size_t)nd * HID + f * 4);
        const int p = f ^ ((f >> 2) & 7);
        *(float4*)&w_lds[(c << 9) + (p << 2)] = v;
    }

    // swizzled LDS base offsets for this thread's k-slice (h and w share)
    const int sw0 = (((ks * 4 + 0) ^ kl)) << 2;
    const int sw1 = (((ks * 4 + 1) ^ kl)) << 2;
    const int sw2 = (((ks * 4 + 2) ^ kl)) << 2;
    const int sw3 = (((ks * 4 + 3) ^ kl)) << 2;

    // consumer identity: thread tid owns producer tid's cols (2tid, 2tid+1)
    const int cf = tid >> 1;                    // f4 index of the col pair
    const int cp = cf ^ ((cf >> 2) & 7);        // swizzled f4 slot
    float* cdst = h_lds + (cp << 2) + ((tid & 1) << 1);

    float c_state = (nl < 2) ? c0[b * HID + hbase + j] : 0.f;
    float gnext = gp[(size_t)b * G4H + n];      // t = 0 preactivation

    for (int t = 0; t < T_STEPS; ++t) {
        float gval = gnext;

        // ---- stage h(t-1) -> LDS ----
        if (t == 0) {
            // bulk staging from h0 (global, contiguous)
#pragma unroll
            for (int i = 0; i < 16; ++i) {
                const int vi = i * 256 + tid;   // float4 index 0..4095
                float4 v = *(const float4*)(h0 + (size_t)vi * 4);
                const int bb = vi >> 7;         // batch row
                const int f  = vi & 127;        // f4 within row
                const int p  = f ^ ((f >> 2) & 7);
                *(float4*)&h_lds[(bb << 9) + (p << 2)] = v;
            }
        } else {
            // slot staging: RELAXED poll on seq[t-1][tid], then plain reads
            const unsigned tag = scan_base + (unsigned)t;
            const unsigned* sp = seq + ((size_t)(t - 1) * 256 + tid);
            unsigned v = __hip_atomic_load(sp, __ATOMIC_RELAXED,
                                           __HIP_MEMORY_SCOPE_AGENT);
            while (v != tag) {
                __builtin_amdgcn_s_sleep(1);
                v = __hip_atomic_load(sp, __ATOMIC_RELAXED,
                                      __HIP_MEMORY_SCOPE_AGENT);
            }
            asm volatile("" ::: "memory");      // no compiler hoist of reads
            const float4* sl =
                (const float4*)(hslab + ((size_t)(t - 1) * 256 + tid) * 64);
            float4 d[16];
#pragma unroll
            for (int i = 0; i < 16; ++i) d[i] = sl[i];
            // slot layout: idx = b*2 + jj  -> d[i] = rows {2i, 2i+1}
#pragma unroll
            for (int i = 0; i < 16; ++i) {
                *(float2*)(cdst + (((2 * i) + 0) << 9)) = make_float2(d[i].x, d[i].y);
                *(float2*)(cdst + (((2 * i) + 1) << 9)) = make_float2(d[i].z, d[i].w);
            }
        }
        __syncthreads();

        // ---- h-tile -> registers (phase-local live range) ----
        float4 hr[4][4];
#pragma unroll
        for (int rr = 0; rr < 4; ++rr) {
            const int o = (bq * 4 + rr) << 9;
            hr[rr][0] = *(const float4*)(h_lds + o + sw0);
            hr[rr][1] = *(const float4*)(h_lds + o + sw1);
            hr[rr][2] = *(const float4*)(h_lds + o + sw2);
            hr[rr][3] = *(const float4*)(h_lds + o + sw3);
        }

        // ---- partial dots: acc[rr*8+c] = h[bq*4+rr][ks*16..+15].w[c] ----
        float acc[32];
#pragma unroll
        for (int c = 0; c < 8; ++c) {
            const int wo = c << 9;
            float4 w0 = *(const float4*)(w_lds + wo + sw0);
            float4 w1 = *(const float4*)(w_lds + wo + sw1);
            float4 w2 = *(const float4*)(w_lds + wo + sw2);
            float4 w3 = *(const float4*)(w_lds + wo + sw3);
#pragma unroll
            for (int rr = 0; rr < 4; ++rr) {
                acc[rr * 8 + c] =
                      (hr[rr][0].x * w0.x + hr[rr][0].y * w0.y
                     + hr[rr][0].z * w0.z + hr[rr][0].w * w0.w)
                    + (hr[rr][1].x * w1.x + hr[rr][1].y * w1.y
                     + hr[rr][1].z * w1.z + hr[rr][1].w * w1.w)
                    + (hr[rr][2].x * w2.x + hr[rr][2].y * w2.y
                     + hr[rr][2].z * w2.z + hr[rr][2].w * w2.w)
                    + (hr[rr][3].x * w3.x + hr[rr][3].y * w3.y
                     + hr[rr][3].z * w3.z + hr[rr][3].w * w3.w);
            }
        }
        {
            float* pw = &part[tid * 36];
#pragma unroll
            for (int i = 0; i < 8; ++i)
                *(float4*)(pw + i * 4) =
                    make_float4(acc[4 * i], acc[4 * i + 1], acc[4 * i + 2], acc[4 * i + 3]);
        }
        __syncthreads();

        // ---- reduce over ks; thread (b,nl) owns output column n ----
        // writer tid = (b>>2)*32 + ks; value index = (b&3)*8 + nl
        float s = gval;
        {
            const float* pr = &part[(b >> 2) * (32 * 36) + (b & 3) * 8 + nl];
#pragma unroll
            for (int kr = 0; kr < 32; ++kr) s += pr[kr * 36];
        }

        // ---- cell: exchange f/g/o via shuffles; owners nl in {0,1} ----
        float fva = __shfl(s, sbase + 2 + j);
        float gva = __shfl(s, sbase + 4 + j);
        float ova = __shfl(s, sbase + 6 + j);
        if (nl < 2) {
            float iv = sigmoidf_(s);
            float fv = sigmoidf_(fva);
            float gv = tanhf(gva);
            float ov = sigmoidf_(ova);
            c_state = fv * c_state + iv * gv;
            float hn = ov * tanhf(c_state);
            // plain store: only later dispatches read h_all
            h_all[((size_t)t * BATCH + b) * HID + hbase + j] = hn;
            // exchange slab: agent write-through store
            if (t < T_STEPS - 1)
                __hip_atomic_store(hslab + ((size_t)t * 256 + bid) * 64 + b * 2 + j,
                                   hn, __ATOMIC_RELAXED, __HIP_MEMORY_SCOPE_AGENT);
        }

        // ---- prefetch next-step preactivation (hides under next poll) ----
        {
            const int tn = (t + 1 < T_STEPS) ? (t + 1) : t;
            gnext = gp[((size_t)tn * BATCH + b) * G4H + n];
        }

        // ---- publish: drain slab stores (vmcnt 0), then post seq ----
        __syncthreads();
        if (t < T_STEPS - 1 && tid == 0)
            __hip_atomic_store(seq + ((size_t)t * 256 + bid),
                               scan_base + (unsigned)(t + 1),
                               __ATOMIC_RELAXED, __HIP_MEMORY_SCOPE_AGENT);
    }
}

// ---------------------------------------------------------------------------
// Softmax over U=1024 (attention weights), in place. One block per (t,b) row.
// ---------------------------------------------------------------------------
__device__ inline float warpReduceMax_(float v) {
#pragma unroll
    for (int o = 32; o > 0; o >>= 1) v = fmaxf(v, __shfl_xor(v, o));
    return v;
}
__device__ inline float warpReduceSum_(float v) {
#pragma unroll
    for (int o = 32; o > 0; o >>= 1) v += __shfl_xor(v, o);
    return v;
}
__device__ inline float blockReduceMax_(float v, float* red) {
    v = warpReduceMax_(v);
    if ((threadIdx.x & 63) == 0) red[threadIdx.x >> 6] = v;
    __syncthreads();
    float r = fmaxf(fmaxf(red[0], red[1]), fmaxf(red[2], red[3]));
    __syncthreads();
    return r;
}
__device__ inline float blockReduceSum_(float v, float* red) {
    v = warpReduceSum_(v);
    if ((threadIdx.x & 63) == 0) red[threadIdx.x >> 6] = v;
    __syncthreads();
    float r = (red[0] + red[1]) + (red[2] + red[3]);
    __syncthreads();
    return r;
}

__global__ __launch_bounds__(256)
void softmax_u(float* __restrict__ s)
{
    __shared__ float red[4];
    float4* p = (float4*)(s + (size_t)blockIdx.x * ULEN);
    float4 v = p[threadIdx.x];
    float mx = fmaxf(fmaxf(v.x, v.y), fmaxf(v.z, v.w));
    mx = blockReduceMax_(mx, red);
    v.x = expf(v.x - mx); v.y = expf(v.y - mx);
    v.z = expf(v.z - mx); v.w = expf(v.w - mx);
    float sm = blockReduceSum_(v.x + v.y + v.z + v.w, red);
    float inv = 1.f / sm;
    v.x *= inv; v.y *= inv; v.z *= inv; v.w *= inv;
    p[threadIdx.x] = v;
}

// ---------------------------------------------------------------------------
// Softmax over V=10000 (output), in place. Row in 40 registers/thread.
// ---------------------------------------------------------------------------
__global__ __launch_bounds__(256)
void softmax_v(float* __restrict__ out)
{
    __shared__ float red[4];
    float* p = out + (size_t)blockIdx.x * VOCAB;
    float v[40];
    float mx = -INFINITY;
#pragma unroll
    for (int k = 0; k < 40; ++k) {
        const int i = (k << 8) + (int)threadIdx.x;
        v[k] = (i < VOCAB) ? p[i] : -INFINITY;
        mx = fmaxf(mx, v[k]);
    }
    mx = blockReduceMax_(mx, red);
    float sm = 0.f;
#pragma unroll
    for (int k = 0; k < 40; ++k) {
        v[k] = expf(v[k] - mx);     // expf(-inf) = 0 for tail lanes
        sm += v[k];
    }
    sm = blockReduceSum_(sm, red);
    const float inv = 1.f / sm;
#pragma unroll
    for (int k = 0; k < 40; ++k) {
        const int i = (k << 8) + (int)threadIdx.x;
        if (i < VOCAB) p[i] = v[k] * inv;
    }
}

// ---------------------------------------------------------------------------
// Prep: combined biases (b_ih + b_hh). Seq words need no zeroing: polls
// compare against exact tags (0x1xx/0x2xx) which never equal 0xAA poison.
// ---------------------------------------------------------------------------
__global__ void prep(const float* __restrict__ bi1, const float* __restrict__ bh1,
                     const float* __restrict__ bi2, const float* __restrict__ bh2,
                     float* __restrict__ bias1, float* __restrict__ bias2)
{
    int i = blockIdx.x * 256 + threadIdx.x;
    if (i < G4H) { bias1[i] = bi1[i] + bh1[i]; bias2[i] = bi2[i] + bh2[i]; }
}

// ---------------------------------------------------------------------------
extern "C" void kernel_launch(void* const* d_in, const int* in_sizes, int n_in,
                              void* d_out, int out_size, void* d_ws, size_t ws_size,
                              hipStream_t stream)
{
    const float* inputs = (const float*)d_in[0];   // (T,B,E)
    const float* h0     = (const float*)d_in[1];   // (2,B,H)
    const float* c0     = (const float*)d_in[2];   // (2,B,H)
    const float* L      = (const float*)d_in[3];   // (U,B,H)
    const float* W_ih1  = (const float*)d_in[4];   // (4H,E)
    const float* W_hh1  = (const float*)d_in[5];   // (4H,H)
    const float* b_ih1  = (const float*)d_in[6];
    const float* b_hh1  = (const float*)d_in[7];
    const float* W_ih2  = (const float*)d_in[8];   // (4H,H)
    const float* W_hh2  = (const float*)d_in[9];   // (4H,H)
    const float* b_ih2  = (const float*)d_in[10];
    const float* b_hh2  = (const float*)d_in[11];
    const float* W_out  = (const float*)d_in[12];  // (V,H)
    const float* b_out  = (const float*)d_in[13];  // (V)
    float* out = (float*)d_out;                    // (T,B,V) fp32

    // Workspace layout (~59 MB). Aliases (all over DEAD regions at use time):
    //   scores over gates; hslab over ctx (free during scan-1 [not yet
    //   written] and dead during scan-2 [last read by X2 GEMM]); bf16 A-pair
    //   over h1 (dead after scores GEMM), B-pair over gates (dead after
    //   scan-2) — both written only after scan-2.
    float* ws    = (float*)d_ws;
    float* gates = ws;                                        // T*B*4H (32MB)
    float* h1    = gates + (size_t)T_STEPS * BATCH * G4H;     // T*B*H (8MB)
    float* h2    = h1    + (size_t)T_STEPS * BATCH * HID;     // T*B*H
    float* ctx   = h2    + (size_t)T_STEPS * BATCH * HID;     // T*B*H
    float* bias1 = ctx   + (size_t)T_STEPS * BATCH * HID;     // 4H
    float* bias2 = bias1 + G4H;                               // 4H
    unsigned* seq = (unsigned*)(bias2 + G4H);                 // T*256 u32
    float* scores = gates;                                    // alias (T,B,U)
    float* hslab  = ctx;                                      // alias (T,256,64)

    const int MA = T_STEPS * BATCH;                           // 4096
    unsigned short* ahi = (unsigned short*)h1;                // 4096*512 bf16
    unsigned short* alo = ahi + (size_t)MA * HID;
    unsigned short* bhi = (unsigned short*)gates;             // 10000*512 bf16
    unsigned short* blo = bhi + (size_t)VOCAB * HID;

    prep<<<8, 256, 0, stream>>>(b_ih1, b_hh1, b_ih2, b_hh2, bias1, bias2);

    // X1 = inputs @ W_ih1^T + (b_ih1+b_hh1)   [4096 x 2048 x 512]
    gemm_f32<true><<<dim3(G4H / 64, MA / 64, 1), 256, 0, stream>>>(
        inputs, EMB, 0, W_ih1, EMB, 0, gates, G4H, 0,
        MA, G4H, EMB, bias1);

    // Layer-1 scan -> h1_all
    lstm_scan<<<256, 256, 0, stream>>>(gates, W_hh1, h0, c0, h1, hslab, seq, 0x100u);

    // scores[t,b,u] = h1[t,b,:] . L[u,b,:]   batched over b (NT GEMM)
    gemm_f32<true><<<dim3(ULEN / 64, T_STEPS / 64, BATCH), 256, 0, stream>>>(
        h1, (long)BATCH * HID, HID,
        L,  (long)BATCH * HID, HID,
        scores, (long)BATCH * ULEN, ULEN,
        T_STEPS, ULEN, HID, nullptr);

    softmax_u<<<T_STEPS * BATCH, 256, 0, stream>>>(scores);

    // ctx[t,b,h] = sum_u w[t,b,u] * L[u,b,h]  batched over b (NN GEMM, K=U)
    gemm_f32<false><<<dim3(HID / 64, T_STEPS / 64, BATCH), 256, 0, stream>>>(
        scores, (long)BATCH * ULEN, ULEN,
        L,      (long)BATCH * HID,  HID,
        ctx,    (long)BATCH * HID,  HID,
        T_STEPS, HID, ULEN, nullptr);

    // X2 = ctx @ W_ih2^T + (b_ih2+b_hh2)   [4096 x 2048 x 512]
    gemm_f32<true><<<dim3(G4H / 64, MA / 64, 1), 256, 0, stream>>>(
        ctx, HID, 0, W_ih2, HID, 0, gates, G4H, 0,
        MA, G4H, HID, bias2);

    // Layer-2 scan -> h2_all  (ctx dead now; hslab reuses it)
    lstm_scan<<<256, 256, 0, stream>>>(gates, W_hh2, h0 + BATCH * HID, c0 + BATCH * HID,
                                       h2, hslab, seq, 0x200u);

    // bf16 hi/lo conversions (gates & h1 are dead from here on)
    conv_split<<<2048, 256, 0, stream>>>(W_out, bhi, blo, VOCAB * HID);
    conv_split<<<2048, 256, 0, stream>>>(h2, ahi, alo, MA * HID);

    // logits = h2 @ W_out^T + b_out via 3-pass bf16-split MFMA -> d_out
    gemm_bf16s<<<dim3(cdiv(VOCAB, 128), MA / 128, 1), 256, 0, stream>>>(
        ahi, alo, bhi, blo, out, b_out, MA, VOCAB, HID);

    softmax_v<<<T_STEPS * BATCH, 256, 0, stream>>>(out);
}

// Round 9
// 2245.634 us; speedup vs baseline: 1.3957x; 1.3957x over previous
//
#include <hip/hip_runtime.h>

// Problem constants (AttentionSpeller): T=128, B=32, E=H=512, U=1024, V=10000
#define T_STEPS 128
#define BATCH   32
#define HID     512
#define EMB     512
#define ULEN    1024
#define VOCAB   10000
#define G4H     2048   // 4*H

// Barrier region: 256 arrive words (stride 16 u32 = 64 B) + 32 go words
// (stride 64 u32 = 256 B). 6144 u32 per scan, two scans.
#define ARR_STRIDE 16
#define GO_OFF     4096
#define GO_STRIDE  64
#define BAR_WORDS  6144

static inline int cdiv(int a, int b) { return (a + b - 1) / b; }

// ---------------------------------------------------------------------------
// Tiled fp32 GEMM, 64x64 tile / 4x4 micro-tile. Best for small-M shapes
// (8+ blocks/CU hide single-buffered staging latency — R5 post-mortem).
// ---------------------------------------------------------------------------
template <bool TRANSB>
__global__ __launch_bounds__(256)
void gemm_f32(const float* __restrict__ A, long lda, long sA,
              const float* __restrict__ Bm, long ldb, long sB,
              float* __restrict__ C, long ldc, long sC,
              int M, int N, int K, const float* __restrict__ bias)
{
    __shared__ float As[16][68];
    __shared__ float Bs[16][68];
    const int bz = blockIdx.z;
    A  += (size_t)bz * sA;
    Bm += (size_t)bz * sB;
    C  += (size_t)bz * sC;
    const int m0 = blockIdx.y * 64;
    const int n0 = blockIdx.x * 64;
    const int tid = threadIdx.x;
    const int tx = tid & 15, ty = tid >> 4;
    const int lr = tid >> 2;          // 0..63: tile row
    const int lk = (tid & 3) * 4;     // 0,4,8,12: k offset

    float acc[4][4] = {{0.f}};

    for (int k0 = 0; k0 < K; k0 += 16) {
        float4 av = *(const float4*)(A + (size_t)(m0 + lr) * lda + (k0 + lk));
        As[lk + 0][lr] = av.x; As[lk + 1][lr] = av.y;
        As[lk + 2][lr] = av.z; As[lk + 3][lr] = av.w;
        if (TRANSB) {
            const int nr = n0 + lr;
            float4 bv = make_float4(0.f, 0.f, 0.f, 0.f);
            if (nr < N) bv = *(const float4*)(Bm + (size_t)nr * ldb + (k0 + lk));
            Bs[lk + 0][lr] = bv.x; Bs[lk + 1][lr] = bv.y;
            Bs[lk + 2][lr] = bv.z; Bs[lk + 3][lr] = bv.w;
        } else {
            const int kr = tid >> 4;          // 0..15
            const int nc = (tid & 15) * 4;    // 0..60
            float4 bv = make_float4(0.f, 0.f, 0.f, 0.f);
            if (n0 + nc < N) bv = *(const float4*)(Bm + (size_t)(k0 + kr) * ldb + (n0 + nc));
            *(float4*)&Bs[kr][nc] = bv;
        }
        __syncthreads();
#pragma unroll
        for (int kk = 0; kk < 16; ++kk) {
            float ar[4], br[4];
#pragma unroll
            for (int i = 0; i < 4; i++) ar[i] = As[kk][ty * 4 + i];
#pragma unroll
            for (int j = 0; j < 4; j++) br[j] = Bs[kk][tx * 4 + j];
#pragma unroll
            for (int i = 0; i < 4; i++)
#pragma unroll
                for (int j = 0; j < 4; j++)
                    acc[i][j] += ar[i] * br[j];
        }
        __syncthreads();
    }
#pragma unroll
    for (int i = 0; i < 4; i++) {
        const int row = m0 + ty * 4 + i;
#pragma unroll
        for (int j = 0; j < 4; j++) {
            const int col = n0 + tx * 4 + j;
            if (col < N) {
                float v = acc[i][j];
                if (bias) v += bias[col];
                C[(size_t)row * ldc + col] = v;
            }
        }
    }
}

// ---------------------------------------------------------------------------
// bf16 split helpers: a = hi + lo with hi = bf16_rne(a), lo = bf16_rne(a-hi).
// Products hi*hi, hi*lo, lo*hi are exact in fp32; dropped lo*lo ~ 2^-17|ab|.
// ---------------------------------------------------------------------------
__device__ inline unsigned short f32_bf16(float x) {
    unsigned u = __float_as_uint(x);
    unsigned r = (u + 0x7FFFu + ((u >> 16) & 1u)) >> 16;
    return (unsigned short)r;
}
__device__ inline float bf16_f32(unsigned short h) {
    return __uint_as_float(((unsigned)h) << 16);
}

// Split src[N] f32 -> dhi[N], dlo[N] bf16. Grid-stride.
__global__ __launch_bounds__(256)
void conv_split(const float* __restrict__ src, unsigned short* __restrict__ dhi,
                unsigned short* __restrict__ dlo, int n)
{
    for (int i = blockIdx.x * 256 + threadIdx.x; i < n; i += gridDim.x * 256) {
        float a = src[i];
        unsigned short hi = f32_bf16(a);
        float r = a - bf16_f32(hi);
        dhi[i] = hi;
        dlo[i] = f32_bf16(r);
    }
}

// ---------------------------------------------------------------------------
// MFMA bf16-split GEMM v2: C[M,N] = A*B^T + bias, fp32-accurate via 3 passes
//   (Ahi*Bhi + Ahi*Blo + Alo*Bhi), A,B stored as bf16 hi/lo pairs [.,K].
// 128x128 tile, 4 waves in 2x2 (each 64x64 = 4x4 frags of 16x16x32 MFMA).
// v2: DOUBLE-BUFFERED LDS staging — R7 post-mortem showed each k-iter had
// only ~150cyc of MFMA to hide a ~300-500cyc global load issued serially
// before it. Now next-tile loads are issued BEFORE the MFMA block and
// written to the alternate buffer after it (write-after-read hazard covered
// by the two barriers). M % 128 == 0; N guarded; K % 32 == 0.
// ---------------------------------------------------------------------------
typedef __attribute__((ext_vector_type(8))) short bf16x8;
typedef __attribute__((ext_vector_type(4))) float f32x4;

__global__ __launch_bounds__(256)
void gemm_bf16s(const unsigned short* __restrict__ Ahi,
                const unsigned short* __restrict__ Alo,
                const unsigned short* __restrict__ Bhi,
                const unsigned short* __restrict__ Blo,
                float* __restrict__ C, const float* __restrict__ bias,
                int M, int N, int K)
{
    __shared__ unsigned short Asm[2][128 * 32];    // 2 x 8 KB
    __shared__ unsigned short Bsm[2][128 * 32];    // 2 x 8 KB
    const int tid = threadIdx.x;
    const int m0 = blockIdx.y * 128;
    const int n0 = blockIdx.x * 128;
    const int w  = tid >> 6;                    // wave 0..3
    const int l  = tid & 63;
    const int wr = (w >> 1) * 64;               // wave row offset
    const int wc = (w & 1) * 64;                // wave col offset
    const int fr = l & 15;                      // frag row/col
    const int kb = l >> 4;                      // k-block 0..3 (8 bf16 each)

    f32x4 acc[4][4];
#pragma unroll
    for (int i = 0; i < 4; ++i)
#pragma unroll
        for (int j = 0; j < 4; ++j) acc[i][j] = (f32x4){0.f, 0.f, 0.f, 0.f};

    const int srow = tid >> 1;                  // staging row 0..127
    const int skh  = (tid & 1) * 16;            // staging k-offset (16 bf16)
    const int nr   = n0 + srow;                 // B staging source row
    const int NK   = K / 32;                    // k-iterations per pass

#pragma unroll 1
    for (int pass = 0; pass < 3; ++pass) {
        const unsigned short* Ap = (pass == 2) ? Alo : Ahi;
        const unsigned short* Bp = (pass == 1) ? Blo : Bhi;
        const unsigned short* arow = Ap + (size_t)(m0 + srow) * K + skh;
        const unsigned short* brow = Bp + (size_t)nr * K + skh;

        // ---- prologue: stage k-tile 0 into buffer 0 ----
        {
            float4 a0 = *(const float4*)(arow);
            float4 a1 = *(const float4*)(arow + 8);
            float4 b0 = make_float4(0.f, 0.f, 0.f, 0.f), b1 = b0;
            if (nr < N) {
                b0 = *(const float4*)(brow);
                b1 = *(const float4*)(brow + 8);
            }
            *(float4*)&Asm[0][srow * 32 + skh] = a0;
            *(float4*)&Asm[0][srow * 32 + skh + 8] = a1;
            *(float4*)&Bsm[0][srow * 32 + skh] = b0;
            *(float4*)&Bsm[0][srow * 32 + skh + 8] = b1;
        }
        __syncthreads();

#pragma unroll 1
        for (int kt = 0; kt < NK; ++kt) {
            const int cur = kt & 1;
            // ---- issue next-tile global loads (hidden under MFMAs) ----
            float4 a0, a1, b0, b1;
            const bool pf = (kt + 1 < NK);
            if (pf) {
                const int ko = (kt + 1) * 32;
                a0 = *(const float4*)(arow + ko);
                a1 = *(const float4*)(arow + ko + 8);
                b0 = make_float4(0.f, 0.f, 0.f, 0.f); b1 = b0;
                if (nr < N) {
                    b0 = *(const float4*)(brow + ko);
                    b1 = *(const float4*)(brow + ko + 8);
                }
            }
            // ---- MFMAs on current buffer ----
            bf16x8 af[4], bf[4];
#pragma unroll
            for (int i = 0; i < 4; ++i)
                af[i] = *(const bf16x8*)&Asm[cur][(wr + i * 16 + fr) * 32 + kb * 8];
#pragma unroll
            for (int j = 0; j < 4; ++j)
                bf[j] = *(const bf16x8*)&Bsm[cur][(wc + j * 16 + fr) * 32 + kb * 8];
#pragma unroll
            for (int i = 0; i < 4; ++i)
#pragma unroll
                for (int j = 0; j < 4; ++j)
                    acc[i][j] = __builtin_amdgcn_mfma_f32_16x16x32_bf16(
                        af[i], bf[j], acc[i][j], 0, 0, 0);
            __syncthreads();
            // ---- write prefetched tile into alternate buffer ----
            if (pf) {
                *(float4*)&Asm[cur ^ 1][srow * 32 + skh] = a0;
                *(float4*)&Asm[cur ^ 1][srow * 32 + skh + 8] = a1;
                *(float4*)&Bsm[cur ^ 1][srow * 32 + skh] = b0;
                *(float4*)&Bsm[cur ^ 1][srow * 32 + skh + 8] = b1;
            }
            __syncthreads();
        }
    }

    // ---- epilogue: C/D layout col=lane&15, row=(lane>>4)*4+reg ----
#pragma unroll
    for (int i = 0; i < 4; ++i) {
#pragma unroll
        for (int j = 0; j < 4; ++j) {
            const int col = n0 + wc + j * 16 + fr;
            if (col < N) {
                const float bv = bias ? bias[col] : 0.f;
#pragma unroll
                for (int r = 0; r < 4; ++r) {
                    const int row = m0 + wr + i * 16 + kb * 4 + r;
                    C[(size_t)row * N + col] = acc[i][j][r] + bv;
                }
            }
        }
    }
}

// ---------------------------------------------------------------------------
// Persistent LSTM scan v8 (R5-R7, verbatim — measured 740us). FINAL.
// v6 compute (W in LDS, register h-tile, 48 b128/thread/step) + 2-hop tree
// barrier (relaxed polls, 1 poller/block; ordering via syncthreads
// vmcnt-drain). v7/v9 post-mortems: direct producer->consumer exchange is
// structurally worse — 65k spinning threads serialize the coherence fabric
// (~+3.5us/step even with relaxed polls). Minimize pollers, not hops.
// ---------------------------------------------------------------------------
__device__ inline float sigmoidf_(float x) { return 1.f / (1.f + expf(-x)); }

__global__ __launch_bounds__(256, 1)
void lstm_scan(const float* __restrict__ gp,    // (T*B*2048) x@W_ih^T + b_ih + b_hh
               const float* __restrict__ Whh,   // (2048 x 512) row-major
               const float* __restrict__ h0,    // (B*H) layer slice
               const float* __restrict__ c0,    // (B*H) layer slice
               float* __restrict__ h_all,       // (T*B*H) out
               unsigned* __restrict__ bar)      // zeroed barrier region
{
    __shared__ float h_lds[BATCH * HID];        // 64 KB, XOR-swizzled float4s
    __shared__ float w_lds[8 * HID];            // 16 KB, same swizzle
    __shared__ float part[256 * 36];            // 36 KB partial sums
    unsigned* arrive = bar;
    unsigned* go     = bar + GO_OFF;

    const int tid  = threadIdx.x;
    const int bid  = blockIdx.x;
    const int hbase = bid * 2;

    // dot-phase identity: tid = bq*32 + ks
    const int ks = tid & 31;                    // 0..31 k-slice of 16
    const int bq = tid >> 5;                    // 0..7 batch-quarter (4 rows)
    const int kl = ks & 7;

    // cell-phase identity: tid = b*8 + nl
    const int b    = tid >> 3;                  // 0..31
    const int nl   = tid & 7;                   // 0..7
    const int j    = nl & 1;
    const int lane = tid & 63;
    const int sbase = lane & ~7;                // shuffle group base lane
    const int n = ((nl >> 1) << 9) + hbase + j; // gate column 0..2047

    // ---- stage this block's 8 W_hh rows -> LDS once (swizzled) ----
#pragma unroll
    for (int i = 0; i < 4; ++i) {
        const int vi = i * 256 + tid;           // 0..1023 f4 index
        const int c  = vi >> 7;                 // 0..7 col slot
        const int f  = vi & 127;                // f4 within row
        const int nd = ((c >> 1) << 9) + hbase + (c & 1);
        float4 v = *(const float4*)(Whh + (size_t)nd * HID + f * 4);
        const int p = f ^ ((f >> 2) & 7);
        *(float4*)&w_lds[(c << 9) + (p << 2)] = v;
    }

    // swizzled LDS base offsets for this thread's k-slice (h and w share)
    const int sw0 = (((ks * 4 + 0) ^ kl)) << 2;
    const int sw1 = (((ks * 4 + 1) ^ kl)) << 2;
    const int sw2 = (((ks * 4 + 2) ^ kl)) << 2;
    const int sw3 = (((ks * 4 + 3) ^ kl)) << 2;

    float c_state = (nl < 2) ? c0[b * HID + hbase + j] : 0.f;
    float gnext = gp[(size_t)b * G4H + n];      // t = 0 preactivation

    for (int t = 0; t < T_STEPS; ++t) {
        float gval = gnext;

        // ---- stage h(t-1) -> LDS (plain cached float4 loads) ----
        const float* hsrc = (t == 0) ? h0 : (h_all + (size_t)(t - 1) * (BATCH * HID));
#pragma unroll
        for (int i = 0; i < 16; ++i) {
            const int vi = i * 256 + tid;       // float4 index 0..4095
            float4 v = *(const float4*)(hsrc + (size_t)vi * 4);
            const int bb = vi >> 7;             // batch row
            const int f  = vi & 127;            // f4 within row
            const int p  = f ^ ((f >> 2) & 7);  // swizzled slot (bijective)
            *(float4*)&h_lds[(bb << 9) + (p << 2)] = v;
        }
        __syncthreads();

        // ---- h-tile -> registers (phase-local live range) ----
        float4 hr[4][4];
#pragma unroll
        for (int rr = 0; rr < 4; ++rr) {
            const int o = (bq * 4 + rr) << 9;
            hr[rr][0] = *(const float4*)(h_lds + o + sw0);
            hr[rr][1] = *(const float4*)(h_lds + o + sw1);
            hr[rr][2] = *(const float4*)(h_lds + o + sw2);
            hr[rr][3] = *(const float4*)(h_lds + o + sw3);
        }

        // ---- partial dots: acc[rr*8+c] = h[bq*4+rr][ks*16..+15].w[c] ----
        float acc[32];
#pragma unroll
        for (int c = 0; c < 8; ++c) {
            const int wo = c << 9;
            float4 w0 = *(const float4*)(w_lds + wo + sw0);
            float4 w1 = *(const float4*)(w_lds + wo + sw1);
            float4 w2 = *(const float4*)(w_lds + wo + sw2);
            float4 w3 = *(const float4*)(w_lds + wo + sw3);
#pragma unroll
            for (int rr = 0; rr < 4; ++rr) {
                acc[rr * 8 + c] =
                      (hr[rr][0].x * w0.x + hr[rr][0].y * w0.y
                     + hr[rr][0].z * w0.z + hr[rr][0].w * w0.w)
                    + (hr[rr][1].x * w1.x + hr[rr][1].y * w1.y
                     + hr[rr][1].z * w1.z + hr[rr][1].w * w1.w)
                    + (hr[rr][2].x * w2.x + hr[rr][2].y * w2.y
                     + hr[rr][2].z * w2.z + hr[rr][2].w * w2.w)
                    + (hr[rr][3].x * w3.x + hr[rr][3].y * w3.y
                     + hr[rr][3].z * w3.z + hr[rr][3].w * w3.w);
            }
        }
        {
            float* pw = &part[tid * 36];
#pragma unroll
            for (int i = 0; i < 8; ++i)
                *(float4*)(pw + i * 4) =
                    make_float4(acc[4 * i], acc[4 * i + 1], acc[4 * i + 2], acc[4 * i + 3]);
        }
        __syncthreads();

        // ---- reduce over ks; thread (b,nl) owns output column n ----
        // writer tid = (b>>2)*32 + ks; value index = (b&3)*8 + nl
        float s = gval;
        {
            const float* pr = &part[(b >> 2) * (32 * 36) + (b & 3) * 8 + nl];
#pragma unroll
            for (int kr = 0; kr < 32; ++kr) s += pr[kr * 36];
        }

        // ---- cell: exchange f/g/o via shuffles; owners nl in {0,1} ----
        float fva = __shfl(s, sbase + 2 + j);
        float gva = __shfl(s, sbase + 4 + j);
        float ova = __shfl(s, sbase + 6 + j);
        if (nl < 2) {
            float iv = sigmoidf_(s);
            float fv = sigmoidf_(fva);
            float gv = tanhf(gva);
            float ov = sigmoidf_(ova);
            c_state = fv * c_state + iv * gv;
            float hn = ov * tanhf(c_state);
            // write-through store (agent scope) -> visible at coherence point
            __hip_atomic_store(h_all + ((size_t)t * BATCH + b) * HID + hbase + j,
                               hn, __ATOMIC_RELAXED, __HIP_MEMORY_SCOPE_AGENT);
        }

        // ---- prefetch next-step preactivation (hides under barrier) ----
        {
            const int tn = (t + 1 < T_STEPS) ? (t + 1) : t;
            gnext = gp[((size_t)tn * BATCH + b) * G4H + n];
        }

        // ---- grid barrier (2-hop tree, relaxed polls) ----
        __syncthreads();
        const unsigned want = (unsigned)(t + 1);
        if (bid == 0) {
            if (tid == 0)
                __hip_atomic_store(&arrive[0], want, __ATOMIC_RELAXED,
                                   __HIP_MEMORY_SCOPE_AGENT);
            unsigned v;
            do {
                v = __hip_atomic_load(&arrive[tid * ARR_STRIDE], __ATOMIC_RELAXED,
                                      __HIP_MEMORY_SCOPE_AGENT);
            } while (__syncthreads_count(v >= want) < 256);
            if (tid < 32)
                __hip_atomic_store(&go[tid * GO_STRIDE], want, __ATOMIC_RELAXED,
                                   __HIP_MEMORY_SCOPE_AGENT);
        } else if (tid == 0) {
            __hip_atomic_store(&arrive[bid * ARR_STRIDE], want, __ATOMIC_RELAXED,
                               __HIP_MEMORY_SCOPE_AGENT);
            unsigned g;
            do {
                __builtin_amdgcn_s_sleep(1);
                g = __hip_atomic_load(&go[(bid & 31) * GO_STRIDE], __ATOMIC_RELAXED,
                                      __HIP_MEMORY_SCOPE_AGENT);
            } while (g < want);
        }
        __syncthreads();
    }
}

// ---------------------------------------------------------------------------
// Softmax over U=1024 (attention weights), in place. One block per (t,b) row.
// ---------------------------------------------------------------------------
__device__ inline float warpReduceMax_(float v) {
#pragma unroll
    for (int o = 32; o > 0; o >>= 1) v = fmaxf(v, __shfl_xor(v, o));
    return v;
}
__device__ inline float warpReduceSum_(float v) {
#pragma unroll
    for (int o = 32; o > 0; o >>= 1) v += __shfl_xor(v, o);
    return v;
}
__device__ inline float blockReduceMax_(float v, float* red) {
    v = warpReduceMax_(v);
    if ((threadIdx.x & 63) == 0) red[threadIdx.x >> 6] = v;
    __syncthreads();
    float r = fmaxf(fmaxf(red[0], red[1]), fmaxf(red[2], red[3]));
    __syncthreads();
    return r;
}
__device__ inline float blockReduceSum_(float v, float* red) {
    v = warpReduceSum_(v);
    if ((threadIdx.x & 63) == 0) red[threadIdx.x >> 6] = v;
    __syncthreads();
    float r = (red[0] + red[1]) + (red[2] + red[3]);
    __syncthreads();
    return r;
}

__global__ __launch_bounds__(256)
void softmax_u(float* __restrict__ s)
{
    __shared__ float red[4];
    float4* p = (float4*)(s + (size_t)blockIdx.x * ULEN);
    float4 v = p[threadIdx.x];
    float mx = fmaxf(fmaxf(v.x, v.y), fmaxf(v.z, v.w));
    mx = blockReduceMax_(mx, red);
    v.x = expf(v.x - mx); v.y = expf(v.y - mx);
    v.z = expf(v.z - mx); v.w = expf(v.w - mx);
    float sm = blockReduceSum_(v.x + v.y + v.z + v.w, red);
    float inv = 1.f / sm;
    v.x *= inv; v.y *= inv; v.z *= inv; v.w *= inv;
    p[threadIdx.x] = v;
}

// ---------------------------------------------------------------------------
// Softmax over V=10000 (output), in place. Row in 40 registers/thread.
// ---------------------------------------------------------------------------
__global__ __launch_bounds__(256)
void softmax_v(float* __restrict__ out)
{
    __shared__ float red[4];
    float* p = out + (size_t)blockIdx.x * VOCAB;
    float v[40];
    float mx = -INFINITY;
#pragma unroll
    for (int k = 0; k < 40; ++k) {
        const int i = (k << 8) + (int)threadIdx.x;
        v[k] = (i < VOCAB) ? p[i] : -INFINITY;
        mx = fmaxf(mx, v[k]);
    }
    mx = blockReduceMax_(mx, red);
    float sm = 0.f;
#pragma unroll
    for (int k = 0; k < 40; ++k) {
        v[k] = expf(v[k] - mx);     // expf(-inf) = 0 for tail lanes
        sm += v[k];
    }
    sm = blockReduceSum_(sm, red);
    const float inv = 1.f / sm;
#pragma unroll
    for (int k = 0; k < 40; ++k) {
        const int i = (k << 8) + (int)threadIdx.x;
        if (i < VOCAB) p[i] = v[k] * inv;
    }
}

// ---------------------------------------------------------------------------
// Prep: combined biases (b_ih + b_hh) + zero the barrier flag regions
// (ws is re-poisoned 0xAA before every call). Launch with 48 blocks.
// ---------------------------------------------------------------------------
__global__ void prep(const float* __restrict__ bi1, const float* __restrict__ bh1,
                     const float* __restrict__ bi2, const float* __restrict__ bh2,
                     float* __restrict__ bias1, float* __restrict__ bias2,
                     unsigned* __restrict__ flags)
{
    int i = blockIdx.x * 256 + threadIdx.x;
    if (i < G4H) { bias1[i] = bi1[i] + bh1[i]; bias2[i] = bi2[i] + bh2[i]; }
    if (i < 2 * BAR_WORDS) flags[i] = 0u;
}

// ---------------------------------------------------------------------------
extern "C" void kernel_launch(void* const* d_in, const int* in_sizes, int n_in,
                              void* d_out, int out_size, void* d_ws, size_t ws_size,
                              hipStream_t stream)
{
    const float* inputs = (const float*)d_in[0];   // (T,B,E)
    const float* h0     = (const float*)d_in[1];   // (2,B,H)
    const float* c0     = (const float*)d_in[2];   // (2,B,H)
    const float* L      = (const float*)d_in[3];   // (U,B,H)
    const float* W_ih1  = (const float*)d_in[4];   // (4H,E)
    const float* W_hh1  = (const float*)d_in[5];   // (4H,H)
    const float* b_ih1  = (const float*)d_in[6];
    const float* b_hh1  = (const float*)d_in[7];
    const float* W_ih2  = (const float*)d_in[8];   // (4H,H)
    const float* W_hh2  = (const float*)d_in[9];   // (4H,H)
    const float* b_ih2  = (const float*)d_in[10];
    const float* b_hh2  = (const float*)d_in[11];
    const float* W_out  = (const float*)d_in[12];  // (V,H)
    const float* b_out  = (const float*)d_in[13];  // (V)
    float* out = (float*)d_out;                    // (T,B,V) fp32

    // Workspace layout (~59 MB; scores aliases gates; bf16 hi/lo buffers
    // alias DEAD regions: A-pair over h1 (dead after ctx GEMM), B-pair over
    // gates (dead after scan-2 reads it) — both written only after scan-2.
    float* ws    = (float*)d_ws;
    float* gates = ws;                                        // T*B*4H (32MB)
    float* h1    = gates + (size_t)T_STEPS * BATCH * G4H;     // T*B*H (8MB)
    float* h2    = h1    + (size_t)T_STEPS * BATCH * HID;     // T*B*H
    float* ctx   = h2    + (size_t)T_STEPS * BATCH * HID;     // T*B*H
    float* bias1 = ctx   + (size_t)T_STEPS * BATCH * HID;     // 4H
    float* bias2 = bias1 + G4H;                               // 4H
    unsigned* flags = (unsigned*)(bias2 + G4H);               // 2*6144 u32
    float* scores = gates;                                    // alias (T,B,U)

    const int MA = T_STEPS * BATCH;                           // 4096
    unsigned short* ahi = (unsigned short*)h1;                // 4096*512 bf16 (4MB)
    unsigned short* alo = ahi + (size_t)MA * HID;             // +4MB (within h1)
    unsigned short* bhi = (unsigned short*)gates;             // 10000*512 bf16 (10.24MB)
    unsigned short* blo = bhi + (size_t)VOCAB * HID;          // +10.24MB (within gates)

    prep<<<48, 256, 0, stream>>>(b_ih1, b_hh1, b_ih2, b_hh2, bias1, bias2, flags);

    // X1 = inputs @ W_ih1^T + (b_ih1+b_hh1)   [4096 x 2048 x 512]
    gemm_f32<true><<<dim3(G4H / 64, MA / 64, 1), 256, 0, stream>>>(
        inputs, EMB, 0, W_ih1, EMB, 0, gates, G4H, 0,
        MA, G4H, EMB, bias1);

    // Layer-1 scan -> h1_all
    lstm_scan<<<256, 256, 0, stream>>>(gates, W_hh1, h0, c0, h1, flags);

    // scores[t,b,u] = h1[t,b,:] . L[u,b,:]   batched over b (NT GEMM)
    gemm_f32<true><<<dim3(ULEN / 64, T_STEPS / 64, BATCH), 256, 0, stream>>>(
        h1, (long)BATCH * HID, HID,
        L,  (long)BATCH * HID, HID,
        scores, (long)BATCH * ULEN, ULEN,
        T_STEPS, ULEN, HID, nullptr);

    softmax_u<<<T_STEPS * BATCH, 256, 0, stream>>>(scores);

    // ctx[t,b,h] = sum_u w[t,b,u] * L[u,b,h]  batched over b (NN GEMM, K=U)
    gemm_f32<false><<<dim3(HID / 64, T_STEPS / 64, BATCH), 256, 0, stream>>>(
        scores, (long)BATCH * ULEN, ULEN,
        L,      (long)BATCH * HID,  HID,
        ctx,    (long)BATCH * HID,  HID,
        T_STEPS, HID, ULEN, nullptr);

    // X2 = ctx @ W_ih2^T + (b_ih2+b_hh2)   [4096 x 2048 x 512]
    gemm_f32<true><<<dim3(G4H / 64, MA / 64, 1), 256, 0, stream>>>(
        ctx, HID, 0, W_ih2, HID, 0, gates, G4H, 0,
        MA, G4H, HID, bias2);

    // Layer-2 scan -> h2_all
    lstm_scan<<<256, 256, 0, stream>>>(gates, W_hh2, h0 + BATCH * HID, c0 + BATCH * HID,
                                       h2, flags + BAR_WORDS);

    // bf16 hi/lo conversions (gates & h1 are dead from here on)
    conv_split<<<2048, 256, 0, stream>>>(W_out, bhi, blo, VOCAB * HID);
    conv_split<<<2048, 256, 0, stream>>>(h2, ahi, alo, MA * HID);

    // logits = h2 @ W_out^T + b_out via 3-pass bf16-split MFMA -> d_out
    gemm_bf16s<<<dim3(cdiv(VOCAB, 128), MA / 128, 1), 256, 0, stream>>>(
        ahi, alo, bhi, blo, out, b_out, MA, VOCAB, HID);

    softmax_v<<<T_STEPS * BATCH, 256, 0, stream>>>(out);
}